// Round 9
// baseline (22.530 us; speedup 1.0000x reference)
//
#include <hip/hip_runtime.h>
#include <hip/hip_bf16.h>

#define HW 128

typedef __attribute__((ext_vector_type(8))) short bf16x8;
typedef __attribute__((ext_vector_type(4))) float f32x4;

__device__ __forceinline__ ushort f2bf(float x) {
  uint u = __builtin_bit_cast(uint, x);
  u += 0x7FFFu + ((u >> 16) & 1u);   // RNE; inputs finite
  return (ushort)(u >> 16);
}
__device__ __forceinline__ uint bpack(float a, float b) {
  return (uint)f2bf(a) | ((uint)f2bf(b) << 16);
}

// B layout: Wb[((t*16 + i)*4 + lq)*8 + e]  (bf16), t = n*5+q (45 chunks of 1KB)
// k = q*32 + lq*8 + e = j*10 + c in [0,160)
// value: c==0 -> sum_m base_w; c in 1..8 -> sum_m spline_w[c-1]*scaler; c==9 -> 0
__global__ __launch_bounds__(64) void kan_prep2(const float* __restrict__ bw,
                                                const float* __restrict__ sw,
                                                const float* __restrict__ sc,
                                                ushort* __restrict__ Wb) {
  __shared__ float sws[648];
  __shared__ float bws[81];
  __shared__ float scs[81];
  int l = threadIdx.x;
  int ij = blockIdx.x;          // i*16 + j
  int i = ij >> 4, j = ij & 15;
  const float* swp = sw + ij * 648;
  const float* bwp = bw + ij * 81;
  const float* scp = sc + ij * 81;
#pragma unroll
  for (int t = 0; t < 10; ++t) sws[t * 64 + l] = swp[t * 64 + l];
  if (l < 8) sws[640 + l] = swp[640 + l];
  bws[l < 81 ? l : 80] = bwp[l < 81 ? l : 80];
  if (l < 17) bws[64 + l] = bwp[64 + l];
  scs[l < 81 ? l : 80] = scp[l < 81 ? l : 80];
  if (l < 17) scs[64 + l] = scp[64 + l];
  __syncthreads();
#pragma unroll
  for (int r = 0; r < 2; ++r) {
    int o = r * 64 + l;
    if (o < 90) {
      int n = o / 10, c = o % 10;
      float s = 0.f;
      if (c == 0) {
#pragma unroll
        for (int m = 0; m < 9; ++m) s += bws[m * 9 + n];
      } else if (c <= 8) {
#pragma unroll
        for (int m = 0; m < 9; ++m) s += sws[(m * 9 + n) * 8 + (c - 1)] * scs[m * 9 + n];
      }
      int k = j * 10 + c;
      int q = k >> 5, lq = (k >> 3) & 3, e = k & 7;
      int t = n * 5 + q;
      Wb[((t * 16 + i) * 4 + lq) * 8 + e] = f2bf(s);
    }
  }
}

#define PSTRIDE 336                 // 160 bf16 (k=j*10+c) + 16B pad; bank-uniform b128s
#define HALO_PX 180                 // 10 rows x 18 cols

// Dense uniform cubic B-spline: basis_s(x) = N3(t - s), t = (x+2.2)*2.5.
// N3 via a=|tau-2|: a<1 ? 0.5a^3 - a^2 + 2/3 : max(0,2-a)^3/6. Support/clamp implicit.
__device__ __forceinline__ float bspline_slot(float t, int s) {
  float a = fabsf(t - (float)(s + 2));
  float w = fmaxf(2.0f - a, 0.0f);
  float cube = w * w * w * (1.0f / 6.0f);
  float poly = fmaf(a * a, fmaf(0.5f, a, -1.0f), 2.0f / 3.0f);
  return (a < 1.0f) ? poly : cube;
}

__global__ __launch_bounds__(256, 2) void kan_mfma(
    const float* __restrict__ X, const ushort* __restrict__ Wb,
    const float* __restrict__ bias, float* __restrict__ out) {
  __shared__ char smem[HALO_PX * PSTRIDE];   // 60480 B

  int tid = threadIdx.x;
  int lane = tid & 63;
  int wid = tid >> 6;                 // 4 waves; wave owns output rows wid, wid+4
  int bid = blockIdx.x;
  int b = bid >> 7;
  int tile = bid & 127;
  int h0 = (tile >> 3) << 3;          // 16 row-tiles of 8
  int w0 = (tile & 7) << 4;           // 8 col-tiles of 16
  int li = lane & 15;
  int lq = lane >> 4;

  const char* wbase = (const char*)Wb + li * 64 + lq * 16;

  // Single-buffered B-frags: 15 chunks = 60 VGPRs.
  // Sub-pass 0 issued before features: L2 latency hides under feature phase.
  bf16x8 Bbuf[15];
#pragma unroll
  for (int t = 0; t < 15; ++t)
    Bbuf[t] = *(const bf16x8*)(wbase + t * 1024);

  // ---- feature phase: 720 quad-tasks (180 px x 4 channel-quads) ----
  // Dense compute in registers, then 5 x ds_write_b128 (16B-aligned, bank-uniform).
#pragma unroll
  for (int r = 0; r < 3; ++r) {
    int tq = r * 256 + tid;
    if (tq < 720) {
      int p = tq >> 2, jq = tq & 3;
      int hh = p / 18, ww = p - hh * 18;
      int gh = h0 + hh - 1, gw = w0 + ww - 1;
      bool inb = (gh >= 0) & (gh < HW) & (gw >= 0) & (gw < HW);
      const float* xp = X + ((b * 16 + jq * 4) << 14) + (gh << 7) + gw;
      uint W[20];
#pragma unroll
      for (int jl = 0; jl < 4; ++jl) {
        float xv = inb ? xp[jl << 14] : 0.f;  // pad pixel: x=0, features still stored
        float sil = __fdividef(xv, 1.0f + __expf(-xv));
        float t = (xv + 2.2f) * 2.5f;
        float n0 = bspline_slot(t, 0), n1 = bspline_slot(t, 1);
        float n2 = bspline_slot(t, 2), n3 = bspline_slot(t, 3);
        float n4 = bspline_slot(t, 4), n5 = bspline_slot(t, 5);
        float n6 = bspline_slot(t, 6), n7 = bspline_slot(t, 7);
        W[jl * 5 + 0] = bpack(sil, n0);
        W[jl * 5 + 1] = bpack(n1, n2);
        W[jl * 5 + 2] = bpack(n3, n4);
        W[jl * 5 + 3] = bpack(n5, n6);
        W[jl * 5 + 4] = (uint)f2bf(n7);      // (n7, 0): slot 9 is the k-pad
      }
      char* qp = smem + p * PSTRIDE + jq * 80;
#pragma unroll
      for (int w = 0; w < 5; ++w) {
        uint4 v = make_uint4(W[w * 4 + 0], W[w * 4 + 1], W[w * 4 + 2], W[w * 4 + 3]);
        *reinterpret_cast<uint4*>(qp + w * 16) = v;
      }
    }
  }
  __syncthreads();

  // ---- MFMA phase: 3 sub-passes x (5 chunks x 3 taps) x 2 rows ----
  f32x4 acc0 = {0.f, 0.f, 0.f, 0.f};
  f32x4 acc1 = {0.f, 0.f, 0.f, 0.f};
  int ab = li * PSTRIDE + lq * 16;
  const char* base0 = smem + wid * (18 * PSTRIDE) + ab;          // row wid
  const char* base1 = smem + (wid + 4) * (18 * PSTRIDE) + ab;    // row wid+4

#pragma unroll
  for (int s = 0; s < 3; ++s) {
#pragma unroll
    for (int tt = 0; tt < 15; ++tt) {
      const int t = s * 15 + tt;
      const int n = t / 5, q = t - n * 5;
      const int dh = n / 3, dw = n - dh * 3;
      const int imm = (dh * 18 + dw) * PSTRIDE + q * 64;
      bf16x8 a0 = *(const bf16x8*)(base0 + imm);
      acc0 = __builtin_amdgcn_mfma_f32_16x16x32_bf16(a0, Bbuf[tt], acc0, 0, 0, 0);
      bf16x8 a1 = *(const bf16x8*)(base1 + imm);
      acc1 = __builtin_amdgcn_mfma_f32_16x16x32_bf16(a1, Bbuf[tt], acc1, 0, 0, 0);
      if (s < 2)
        Bbuf[tt] = *(const bf16x8*)(wbase + ((s + 1) * 15 + tt) * 1024);
    }
  }

  // ---- epilogue: lane holds i=li, pixels w = lq*4 + reg, rows wid / wid+4 ----
  float bias_v = bias[li];
  float* op0 = out + ((b * 16 + li) << 14) + ((h0 + wid) << 7) + w0 + lq * 4;
  float* op1 = out + ((b * 16 + li) << 14) + ((h0 + wid + 4) << 7) + w0 + lq * 4;
  float4 v0, v1;
  v0.x = acc0[0] + bias_v; v0.y = acc0[1] + bias_v;
  v0.z = acc0[2] + bias_v; v0.w = acc0[3] + bias_v;
  v1.x = acc1[0] + bias_v; v1.y = acc1[1] + bias_v;
  v1.z = acc1[2] + bias_v; v1.w = acc1[3] + bias_v;
  *reinterpret_cast<float4*>(op0) = v0;
  *reinterpret_cast<float4*>(op1) = v1;
}

extern "C" void kernel_launch(void* const* d_in, const int* in_sizes, int n_in,
                              void* d_out, int out_size, void* d_ws, size_t ws_size,
                              hipStream_t stream) {
  const float* x    = (const float*)d_in[0];
  const float* bw   = (const float*)d_in[1];
  const float* sw   = (const float*)d_in[2];
  const float* sc   = (const float*)d_in[3];
  const float* bias = (const float*)d_in[4];
  float* out = (float*)d_out;
  ushort* Wb = (ushort*)d_ws;   // 45*512 bf16 = 46080 B

  hipLaunchKernelGGL(kan_prep2, dim3(256), dim3(64), 0, stream, bw, sw, sc, Wb);
  hipLaunchKernelGGL(kan_mfma, dim3(512), dim3(256), 0, stream, x, Wb, bias, out);
}